// Round 10
// baseline (258.393 us; speedup 1.0000x reference)
//
#include <hip/hip_runtime.h>
#include <cstdint>
#include <cstddef>

// ---------------------------------------------------------------------------
// NAMAttention round 10: round-9 assembly + occupancy bumps only.
//  - qkv: 128x128/BK=32 core with __launch_bounds__(256,4) -> 4 blocks/CU
//    (LDS 4x32KB=128<=160KB; regs 60+64acc=124<=128/wave at 4 waves/EU).
//  - o2: __launch_bounds__(256,3) (24KB LDS -> 3 blocks/CU fits).
//  - everything else byte-identical to round 9.
// ---------------------------------------------------------------------------

typedef __bf16 bf16x8 __attribute__((ext_vector_type(8)));
typedef float  f32x4  __attribute__((ext_vector_type(4)));
typedef unsigned short u16x8 __attribute__((ext_vector_type(8)));
typedef unsigned short u16x4 __attribute__((ext_vector_type(4)));

#define ROWS 16384      // S*B
#define DM   1024

__device__ __forceinline__ unsigned short f2bf(float f) {
  unsigned int u = __builtin_bit_cast(unsigned int, f);
  u += 0x7FFFu + ((u >> 16) & 1u);            // round-to-nearest-even
  return (unsigned short)(u >> 16);
}
__device__ __forceinline__ float bf2f(unsigned short h) {
  unsigned int u = ((unsigned int)h) << 16;
  return __builtin_bit_cast(float, u);
}
__device__ __forceinline__ float sigm(float x) { return 1.0f / (1.0f + __expf(-x)); }

__device__ __forceinline__ void gload_lds16(const void* g, void* l) {
  __builtin_amdgcn_global_load_lds((__attribute__((address_space(1))) void*)(g),
                                   (__attribute__((address_space(3))) void*)(l),
                                   16, 0, 0);
}

// ---------------- cast input to bf16 ----------------
__global__ __launch_bounds__(256) void k_cast_x(const float* __restrict__ X,
                                                unsigned short* __restrict__ Xb) {
  size_t i = ((size_t)blockIdx.x * 256 + threadIdx.x) * 8;
  f32x4 a = *(const f32x4*)(X + i);
  f32x4 b = *(const f32x4*)(X + i + 4);
  u16x8 o;
  o[0] = f2bf(a[0]); o[1] = f2bf(a[1]); o[2] = f2bf(a[2]); o[3] = f2bf(a[3]);
  o[4] = f2bf(b[0]); o[5] = f2bf(b[1]); o[6] = f2bf(b[2]); o[7] = f2bf(b[3]);
  *(u16x8*)(Xb + i) = o;
}

// ---------------- pack weights (bf16) + biases ----------------
__global__ __launch_bounds__(256) void k_pack_w(
    const float* __restrict__ Wq, const float* __restrict__ Wk, const float* __restrict__ Wv,
    const float* __restrict__ Wo, const float* __restrict__ Ww, const float* __restrict__ Wr,
    const float* __restrict__ bq, const float* __restrict__ bk, const float* __restrict__ bv,
    const float* __restrict__ bw, const float* __restrict__ br,
    unsigned short* __restrict__ Wpack, float* __restrict__ biasP,
    unsigned short* __restrict__ WRw, float* __restrict__ biasWR,
    unsigned short* __restrict__ Wob) {
  int r = blockIdx.x, t = threadIdx.x;
  const float* src; float bias = 0.0f; unsigned short* dst; float* bdst;
  if (r < 1024)      { src = Wq + (size_t)r * DM;          bias = bq[r];        dst = Wpack + (size_t)r * DM;          bdst = biasP + r; }
  else if (r < 2048) { src = Wk + (size_t)(r - 1024) * DM; bias = bk[r - 1024]; dst = Wpack + (size_t)r * DM;          bdst = biasP + r; }
  else if (r < 3072) { src = Wv + (size_t)(r - 2048) * DM; bias = bv[r - 2048]; dst = Wpack + (size_t)r * DM;          bdst = biasP + r; }
  else if (r < 3088) { src = Ww + (size_t)(r - 3072) * DM; bias = bw[r - 3072]; dst = WRw + (size_t)(r - 3072) * DM;   bdst = biasWR + (r - 3072); }
  else if (r < 3104) { src = Wr + (size_t)(r - 3088) * DM; bias = br[r - 3088]; dst = WRw + (size_t)(r - 3072) * DM;   bdst = biasWR + (r - 3072); }
  else               { src = Wo + (size_t)(r - 3104) * DM;                      dst = Wob + (size_t)(r - 3104) * DM;   bdst = nullptr; }
  int c = t * 4;
  f32x4 v = *(const f32x4*)(src + c);
  u16x4 o;
  o[0] = f2bf(v[0]); o[1] = f2bf(v[1]); o[2] = f2bf(v[2]); o[3] = f2bf(v[3]);
  *(u16x4*)(dst + c) = o;
  if (t == 0 && bdst) *bdst = bias;
}

// ---------------- w/r logits: WRf[row,0..31] = X @ [Ww;Wr]^T + b ----------------
__global__ __launch_bounds__(256) void k_wr(const unsigned short* __restrict__ Xb,
                                            const unsigned short* __restrict__ WRw,
                                            const float* __restrict__ biasWR,
                                            float* __restrict__ WRf) {
  __shared__ __bf16 sA[128 * 64];
  __shared__ __bf16 sB[32 * 64];
  int t = threadIdx.x, lane = t & 63, wid = t >> 6;
  int m0 = blockIdx.x * 128;
  int l15 = lane & 15, l4 = lane >> 4;
  f32x4 acc[2][2];
#pragma unroll
  for (int i = 0; i < 2; ++i)
#pragma unroll
    for (int j = 0; j < 2; ++j) acc[i][j] = (f32x4){0.f, 0.f, 0.f, 0.f};
  int srow = t >> 3, schunk = (t & 7) * 8;
  for (int kt = 0; kt < DM; kt += 64) {
#pragma unroll
    for (int c = 0; c < 4; ++c)
      gload_lds16(Xb + (size_t)(m0 + c * 32 + srow) * DM + kt + schunk,
                  (void*)(sA + c * 2048 + wid * 512));
    gload_lds16(WRw + (size_t)srow * DM + kt + schunk, (void*)(sB + wid * 512));
    __syncthreads();
#pragma unroll
    for (int ks = 0; ks < 2; ++ks) {
      bf16x8 fa[2], fb[2];
#pragma unroll
      for (int mi = 0; mi < 2; ++mi)
        fa[mi] = *(const bf16x8*)(sA + (wid * 32 + mi * 16 + l15) * 64 + (ks * 4 + l4) * 8);
#pragma unroll
      for (int ni = 0; ni < 2; ++ni)
        fb[ni] = *(const bf16x8*)(sB + (ni * 16 + l15) * 64 + (ks * 4 + l4) * 8);
#pragma unroll
      for (int mi = 0; mi < 2; ++mi)
#pragma unroll
        for (int ni = 0; ni < 2; ++ni)
          acc[mi][ni] = __builtin_amdgcn_mfma_f32_16x16x32_bf16(fa[mi], fb[ni], acc[mi][ni], 0, 0, 0);
    }
    __syncthreads();
  }
#pragma unroll
  for (int mi = 0; mi < 2; ++mi)
#pragma unroll
    for (int e = 0; e < 4; ++e) {
      int row = m0 + wid * 32 + mi * 16 + 4 * l4 + e;
#pragma unroll
      for (int ni = 0; ni < 2; ++ni)
        WRf[(size_t)row * 32 + ni * 16 + l15] = acc[mi][ni][e] + biasWR[ni * 16 + l15];
    }
}

// ============== 128x128 BK=32 double-buffered core (32 KiB LDS) ==============
// Buf P at sm + P*8192 elems: A 128x32 at [0,4096), B at [4096,8192).
// 16B chunk c of row r holds global chunk c ^ ((r>>1)&3) (both sides).

#define STAGE128(P, kt)                                                             \
  do {                                                                              \
    _Pragma("unroll") for (int c = 0; c < 2; ++c)                                   \
      gload_lds16(Asrc + (size_t)(c * 64) * DM + (kt),                              \
                  (void*)(sm + (P) * 8192 + c * 2048 + w * 512));                   \
    _Pragma("unroll") for (int c = 0; c < 2; ++c)                                   \
      gload_lds16(Bsrc + (size_t)(c * 64) * DM + (kt),                              \
                  (void*)(sm + (P) * 8192 + 4096 + c * 2048 + w * 512));            \
  } while (0)

__device__ __forceinline__ void gemm128(const unsigned short* __restrict__ Ag,
                                        const unsigned short* __restrict__ Bg,
                                        __bf16* sm, f32x4 (&acc)[4][4],
                                        int m0, int n0, int lane, int w) {
  const int wr = w >> 1, wc = w & 1;
  const int l15 = lane & 15, l4 = lane >> 4;
  const int t = w * 64 + lane;
  const int srow = t >> 2;                              // 0..63 (rows srow, srow+64)
  const int sc = ((t & 3) ^ ((srow >> 1) & 3)) * 8;     // swizzled source chunk
  const unsigned short* Asrc = Ag + (size_t)(m0 + srow) * DM + sc;
  const unsigned short* Bsrc = Bg + (size_t)(n0 + srow) * DM + sc;

  int aoff[4], boff[4];
#pragma unroll
  for (int mi = 0; mi < 4; ++mi) {
    int r = wr * 64 + mi * 16 + l15;
    aoff[mi] = r * 32 + ((l4 ^ ((r >> 1) & 3)) << 3);
  }
#pragma unroll
  for (int ni = 0; ni < 4; ++ni) {
    int r = wc * 64 + ni * 16 + l15;
    boff[ni] = 4096 + r * 32 + ((l4 ^ ((r >> 1) & 3)) << 3);
  }

  STAGE128(0, 0);
  __syncthreads();
  for (int kt = 0; kt < 32; ++kt) {
    int P = kt & 1;
    if (kt < 31) STAGE128(P ^ 1, (kt + 1) * 32);
    const __bf16* base = sm + P * 8192;
    bf16x8 fa[4], fb[4];
#pragma unroll
    for (int mi = 0; mi < 4; ++mi) fa[mi] = *(const bf16x8*)(base + aoff[mi]);
#pragma unroll
    for (int ni = 0; ni < 4; ++ni) fb[ni] = *(const bf16x8*)(base + boff[ni]);
#pragma unroll
    for (int mi = 0; mi < 4; ++mi)
#pragma unroll
      for (int ni = 0; ni < 4; ++ni)
        acc[mi][ni] = __builtin_amdgcn_mfma_f32_16x16x32_bf16(fa[mi], fb[ni], acc[mi][ni], 0, 0, 0);
    __syncthreads();
  }
}

// ---------------- fused QKV GEMM (128^2 core, 4 blocks/CU) ----------------
__global__ __launch_bounds__(256, 4) void k_gemm_qkv10(
    const unsigned short* __restrict__ Xb, const unsigned short* __restrict__ Wpack,
    const float* __restrict__ biasP, const float* __restrict__ WRf,
    unsigned short* __restrict__ Qb, unsigned short* __restrict__ Kb,
    unsigned short* __restrict__ Vb) {
  __shared__ __bf16 sm[16384];                     // 32 KiB, 2 buffers
  const int t = threadIdx.x, lane = t & 63, w = t >> 6;
  const int wr = w >> 1, wc = w & 1;
  const int l15 = lane & 15, l4 = lane >> 4;
  int orig = blockIdx.x;                           // 3072 = 8 * 384
  int wg = (orig & 7) * 384 + (orig >> 3);         // XCD chunks
  const int m0 = (wg / 24) << 7;                   // n-inner
  const int n0 = (wg % 24) << 7;
  f32x4 acc[4][4];
#pragma unroll
  for (int i = 0; i < 4; ++i)
#pragma unroll
    for (int j = 0; j < 4; ++j) acc[i][j] = (f32x4){0.f, 0.f, 0.f, 0.f};
  gemm128(Xb, Wpack, sm, acc, m0, n0, lane, w);

  // ---- epilogue: each wave's 64-col stripe == one head ----
  const int colbase = n0 + wc * 64;
  float bb[4];
#pragma unroll
  for (int ni = 0; ni < 4; ++ni) bb[ni] = biasP[colbase + ni * 16 + l15];

  if (colbase < 2048) {
    unsigned short* dstp = (colbase < 1024) ? Qb : Kb;
    int coff = (colbase < 1024) ? colbase : (colbase - 1024);
#pragma unroll
    for (int mi = 0; mi < 4; ++mi)
#pragma unroll
      for (int e = 0; e < 4; ++e) {
        float v[4]; float ssq = 0.f;
#pragma unroll
        for (int ni = 0; ni < 4; ++ni) { v[ni] = acc[mi][ni][e] + bb[ni]; ssq += v[ni] * v[ni]; }
        ssq += __shfl_xor(ssq, 1);
        ssq += __shfl_xor(ssq, 2);
        ssq += __shfl_xor(ssq, 4);
        ssq += __shfl_xor(ssq, 8);       // full 64-col head (16 lanes x 4)
        float sc2 = 1.0f / fmaxf(sqrtf(ssq), 1e-12f);
        int row = m0 + wr * 64 + mi * 16 + 4 * l4 + e;
#pragma unroll
        for (int ni = 0; ni < 4; ++ni)
          dstp[(size_t)row * DM + coff + ni * 16 + l15] = f2bf(v[ni] * sc2);
      }
  } else {
    int hv = (colbase - 2048) >> 6;
    int coff = colbase - 2048;
#pragma unroll
    for (int mi = 0; mi < 4; ++mi)
#pragma unroll
      for (int e = 0; e < 4; ++e) {
        int row = m0 + wr * 64 + mi * 16 + 4 * l4 + e;
        float wgt = sigm(WRf[(size_t)row * 32 + hv]);
#pragma unroll
        for (int ni = 0; ni < 4; ++ni)
          Vb[(size_t)row * DM + coff + ni * 16 + l15] = f2bf((acc[mi][ni][e] + bb[ni]) * wgt);
      }
  }
}

// ========== 256x256 depth-4 counted-vmcnt + read-ahead core (BK=32) ==========
#define VMW(N)  asm volatile("s_waitcnt vmcnt(" #N ")" ::: "memory")
#define LGKM(N) asm volatile("s_waitcnt lgkmcnt(" #N ")" ::: "memory")
#define SB0     __builtin_amdgcn_sched_barrier(0)

__device__ __forceinline__ void stageT(const unsigned short* __restrict__ Asrc,
                                       const unsigned short* __restrict__ Bsrc,
                                       int kt, __bf16* sm, int sb, int w) {
#pragma unroll
  for (int c = 0; c < 2; ++c)
    gload_lds16(Asrc + (size_t)c * 128 * DM + kt, (void*)(sm + sb + c * 4096 + w * 512));
#pragma unroll
  for (int c = 0; c < 2; ++c)
    gload_lds16(Bsrc + (size_t)c * 128 * DM + kt, (void*)(sm + sb + 8192 + c * 4096 + w * 512));
}

__device__ __forceinline__ void rdFA(bf16x8 (&fa)[8], const __bf16* base, const int (&aoff)[8]) {
#pragma unroll
  for (int mi = 0; mi < 8; ++mi) fa[mi] = *(const bf16x8*)(base + aoff[mi]);
}
__device__ __forceinline__ void rdFB(bf16x8 (&fb)[4], const __bf16* base, const int (&boff)[4]) {
#pragma unroll
  for (int ni = 0; ni < 4; ++ni) fb[ni] = *(const bf16x8*)(base + boff[ni]);
}

#define MFMA32(FB)                                                                   \
  do {                                                                               \
    __builtin_amdgcn_s_setprio(1);                                                   \
    _Pragma("unroll") for (int mi = 0; mi < 8; ++mi)                                 \
    _Pragma("unroll") for (int ni = 0; ni < 4; ++ni)                                 \
      acc[mi][ni] = __builtin_amdgcn_mfma_f32_16x16x32_bf16(fa[mi], FB[ni],          \
                                                            acc[mi][ni], 0, 0, 0);  \
    __builtin_amdgcn_s_setprio(0);                                                   \
    SB0;                                                                             \
  } while (0)

__device__ __forceinline__ void gemm_d4(const unsigned short* __restrict__ Ag,
                                        const unsigned short* __restrict__ Bg,
                                        __bf16* sm, f32x4 (&acc)[8][4],
                                        int m0, int n0, int lane, int w) {
  const int wm = w >> 2, wn = w & 3;
  const int l15 = lane & 15, l4 = lane >> 4;
  const int t = w * 64 + lane;
  const int srow = t >> 2;
  const int schunk = ((t & 3) ^ ((srow >> 1) & 3)) * 8;
  const unsigned short* Asrc = Ag + (size_t)(m0 + srow) * DM + schunk;
  const unsigned short* Bsrc = Bg + (size_t)(n0 + srow) * DM + schunk;

  int aoff[8], boff[4];
#pragma unroll
  for (int mi = 0; mi < 8; ++mi) {
    int r = wm * 128 + mi * 16 + l15;
    aoff[mi] = r * 32 + ((l4 ^ ((r >> 1) & 3)) << 3);
  }
#pragma unroll
  for (int ni = 0; ni < 4; ++ni) {
    int r = wn * 64 + ni * 16 + l15;
    boff[ni] = 8192 + r * 32 + ((l4 ^ ((r >> 1) & 3)) << 3);
  }

  bf16x8 fa[8], fbA[4], fbB[4];
  stageT(Asrc, Bsrc, 0,  sm, 0,     w);
  stageT(Asrc, Bsrc, 32, sm, 16384, w);
  stageT(Asrc, Bsrc, 64, sm, 32768, w);
  VMW(8);
  __builtin_amdgcn_s_barrier(); SB0;
  rdFB(fbA, sm, boff);
  rdFA(fa, sm, aoff);
  VMW(4);
  __builtin_amdgcn_s_barrier(); SB0;

  int sb = 49152;
  int rb = 16384;
  for (int i = 0; i < 14; ++i) {
    stageT(Asrc, Bsrc, (2 * i + 3) * 32, sm, sb, w); sb = (sb + 16384) & 65535;
    rdFB(fbB, sm + rb, boff);
    LGKM(4); SB0;
    MFMA32(fbA);
    rdFA(fa, sm + rb, aoff); rb = (rb + 16384) & 65535;
    VMW(4);
    __builtin_amdgcn_s_barrier(); SB0;
    stageT(Asrc, Bsrc, (2 * i + 4) * 32, sm, sb, w); sb = (sb + 16384) & 65535;
    rdFB(fbA, sm + rb, boff);
    LGKM(4); SB0;
    MFMA32(fbB);
    rdFA(fa, sm + rb, aoff); rb = (rb + 16384) & 65535;
    VMW(4);
    __builtin_amdgcn_s_barrier(); SB0;
  }
  stageT(Asrc, Bsrc, 992, sm, sb, w);
  rdFB(fbB, sm + rb, boff);
  LGKM(4); SB0;
  MFMA32(fbA);
  rdFA(fa, sm + rb, aoff); rb = (rb + 16384) & 65535;
  VMW(4);
  __builtin_amdgcn_s_barrier(); SB0;
  rdFB(fbA, sm + rb, boff);
  LGKM(4); SB0;
  MFMA32(fbB);
  rdFA(fa, sm + rb, aoff); rb = (rb + 16384) & 65535;
  VMW(0);
  __builtin_amdgcn_s_barrier(); SB0;
  rdFB(fbB, sm + rb, boff);
  LGKM(4); SB0;
  MFMA32(fbA);
  rdFA(fa, sm + rb, aoff);
  LGKM(0); SB0;
  MFMA32(fbB);
}

// ---------------- final projection (depth-4 core): Out = Ob @ Wo^T + bo ------
__global__ __launch_bounds__(512, 2) void k_gemm_out10(
    const unsigned short* __restrict__ Ob, const unsigned short* __restrict__ Wob,
    const float* __restrict__ bo, float* __restrict__ Out) {
  __shared__ __bf16 sm[65536];
  const int t = threadIdx.x, lane = t & 63, w = t >> 6;
  const int wm = w >> 2, wn = w & 3;
  const int l15 = lane & 15, l4 = lane >> 4;
  int orig = blockIdx.x;
  int wg = (orig & 7) * 32 + (orig >> 3);          // 256 = 8*32
  const int m0 = (wg & 63) << 8;
  const int n0 = (wg >> 6) << 8;
  f32x4 acc[8][4];
#pragma unroll
  for (int i = 0; i < 8; ++i)
#pragma unroll
    for (int j = 0; j < 4; ++j) acc[i][j] = (f32x4){0.f, 0.f, 0.f, 0.f};
  gemm_d4(Ob, Wob, sm, acc, m0, n0, lane, w);

  float bb[4];
#pragma unroll
  for (int ni = 0; ni < 4; ++ni) bb[ni] = bo[n0 + wn * 64 + ni * 16 + l15];
#pragma unroll
  for (int mi = 0; mi < 8; ++mi)
#pragma unroll
    for (int e = 0; e < 4; ++e) {
      int row = m0 + wm * 128 + mi * 16 + 4 * l4 + e;
#pragma unroll
      for (int ni = 0; ni < 4; ++ni) {
        int col = n0 + wn * 64 + ni * 16 + l15;
        Out[(size_t)row * DM + col] = acc[mi][ni][e] + bb[ni];
      }
    }
}

// ---------------- gemm_A split-K=2 ----------------
__global__ __launch_bounds__(256, 2) void k_gemm_A(const unsigned short* __restrict__ Kb,
                                                   const unsigned short* __restrict__ Vb,
                                                   float* __restrict__ Apart) {
  __shared__ __bf16 sK[64 * 64];
  __shared__ __bf16 sV[64 * 64];
  int t = threadIdx.x, lane = t & 63, wid = t >> 6;
  int bn = blockIdx.x & 127, sk = blockIdx.x >> 7;
  int b = bn >> 4, n = bn & 15;
  f32x4 acc[4];
#pragma unroll
  for (int j = 0; j < 4; j++) acc[j] = (f32x4){0.f, 0.f, 0.f, 0.f};
  int lrow = lane >> 3, lcol = (lane & 7) * 8;

  for (int st = sk * 1024; st < (sk + 1) * 1024; st += 64) {
#pragma unroll
    for (int c = 0; c < 2; c++) {
      int r0 = wid * 16 + c * 8;
      size_t g = ((size_t)(st + r0 + lrow) * 8 + b) * DM + n * 64 + lcol;
      gload_lds16(Kb + g, (void*)(sK + r0 * 64));
      gload_lds16(Vb + g, (void*)(sV + r0 * 64));
    }
    __syncthreads();
#pragma unroll
    for (int kk = 0; kk < 64; kk += 32) {
      bf16x8 av, bv[4];
#pragma unroll
      for (int e = 0; e < 8; e++)
        av[e] = sV[(kk + 8 * (lane >> 4) + e) * 64 + wid * 16 + (lane & 15)];
#pragma unroll
      for (int jn = 0; jn < 4; jn++)
#pragma unroll
        for (int e = 0; e < 8; e++)
          bv[jn][e] = sK[(kk + 8 * (lane >> 4) + e) * 64 + jn * 16 + (lane & 15)];
#pragma unroll
      for (int jn = 0; jn < 4; jn++)
        acc[jn] = __builtin_amdgcn_mfma_f32_16x16x32_bf16(av, bv[jn], acc[jn], 0, 0, 0);
    }
    __syncthreads();
  }
  float* Ap = Apart + (size_t)(sk * 128 + bn) * 4096;
#pragma unroll
  for (int jn = 0; jn < 4; jn++) {
#pragma unroll
    for (int e = 0; e < 4; e++) {
      int i = wid * 16 + 4 * (lane >> 4) + e;
      int j = jn * 16 + (lane & 15);
      Ap[i * 64 + j] = acc[jn][e];
    }
  }
}

// ---------------- reduce split-K partials ----------------
__global__ __launch_bounds__(256) void k_reduceA(const float* __restrict__ Apart,
                                                 float* __restrict__ Aout,
                                                 unsigned short* __restrict__ Abf) {
  int bn = blockIdx.x, t = threadIdx.x;
  size_t base = (size_t)bn * 4096 + t * 16;
#pragma unroll
  for (int j = 0; j < 4; ++j) {
    f32x4 x = *(const f32x4*)(Apart + base + j * 4);
    f32x4 y = *(const f32x4*)(Apart + (size_t)128 * 4096 + base + j * 4);
    x += y;
    *(f32x4*)(Aout + base + j * 4) = x;
    u16x4 o;
    o[0] = f2bf(x[0]); o[1] = f2bf(x[1]); o[2] = f2bf(x[2]); o[3] = f2bf(x[3]);
    *(u16x4*)(Abf + base + j * 4) = o;
  }
}

// ---------------- out2 = r * (qhat @ A^T) ----------------
__global__ __launch_bounds__(256, 3) void k_gemm_o2(const unsigned short* __restrict__ Qb,
                                                    const unsigned short* __restrict__ Abf,
                                                    const float* __restrict__ WRf,
                                                    unsigned short* __restrict__ Ob) {
  __shared__ __bf16 sQ[128 * 64];
  __shared__ __bf16 sA[64 * 64];
  int t = threadIdx.x, lane = t & 63, wid = t >> 6;
  int bn = blockIdx.x & 127, stile = blockIdx.x >> 7;
  int b = bn >> 4, n = bn & 15;
  int s0 = stile * 128;
  int lrow = lane >> 3, lcol = (lane & 7) * 8;
#pragma unroll
  for (int c = 0; c < 4; c++) {
    int r0 = wid * 32 + c * 8;
    gload_lds16(Qb + ((size_t)(s0 + r0 + lrow) * 8 + b) * DM + n * 64 + lcol,
                (void*)(sQ + r0 * 64));
  }
#pragma unroll
  for (int c = 0; c < 2; c++) {
    int r0 = wid * 16 + c * 8;
    gload_lds16(Abf + (size_t)bn * 4096 + (size_t)(r0 + lrow) * 64 + lcol,
                (void*)(sA + r0 * 64));
  }
  __syncthreads();
  f32x4 acc[2][4];
#pragma unroll
  for (int i = 0; i < 2; i++)
#pragma unroll
    for (int j = 0; j < 4; j++) acc[i][j] = (f32x4){0.f, 0.f, 0.f, 0.f};
#pragma unroll
  for (int kk = 0; kk < 64; kk += 32) {
    bf16x8 aq[2], bA[4];
#pragma unroll
    for (int mi = 0; mi < 2; mi++)
      aq[mi] = *(const bf16x8*)(sQ + (wid * 32 + mi * 16 + (lane & 15)) * 64 + kk + 8 * (lane >> 4));
#pragma unroll
    for (int ni = 0; ni < 4; ni++)
      bA[ni] = *(const bf16x8*)(sA + (ni * 16 + (lane & 15)) * 64 + kk + 8 * (lane >> 4));
#pragma unroll
    for (int mi = 0; mi < 2; mi++)
#pragma unroll
      for (int ni = 0; ni < 4; ni++)
        acc[mi][ni] = __builtin_amdgcn_mfma_f32_16x16x32_bf16(aq[mi], bA[ni], acc[mi][ni], 0, 0, 0);
  }
#pragma unroll
  for (int mi = 0; mi < 2; mi++) {
#pragma unroll
    for (int e = 0; e < 4; e++) {
      int srow = wid * 32 + mi * 16 + 4 * (lane >> 4) + e;
      size_t row = (size_t)(s0 + srow) * 8 + b;
      float rv = sigm(WRf[row * 32 + 16 + n]);
#pragma unroll
      for (int ni = 0; ni < 4; ni++)
        Ob[row * DM + n * 64 + ni * 16 + (lane & 15)] = f2bf(acc[mi][ni][e] * rv);
    }
  }
}

// ---------------------------------------------------------------------------
extern "C" void kernel_launch(void* const* d_in, const int* in_sizes, int n_in,
                              void* d_out, int out_size, void* d_ws, size_t ws_size,
                              hipStream_t stream) {
  (void)in_sizes; (void)n_in; (void)out_size; (void)ws_size;
  const float* X  = (const float*)d_in[0];
  const float* Wq = (const float*)d_in[1];  const float* bq = (const float*)d_in[2];
  const float* Wk = (const float*)d_in[3];  const float* bk = (const float*)d_in[4];
  const float* Wv = (const float*)d_in[5];  const float* bv = (const float*)d_in[6];
  const float* Wo = (const float*)d_in[7];  const float* bo = (const float*)d_in[8];
  const float* Ww = (const float*)d_in[9];  const float* bw = (const float*)d_in[10];
  const float* Wr = (const float*)d_in[11]; const float* br = (const float*)d_in[12];

  char* ws = (char*)d_ws;
  unsigned short* Wpack = (unsigned short*)(ws + 0);            // 6,291,456
  float*          Apart = (float*)(ws + 0);                     // alias (after qkv10)
  unsigned short* Abf   = (unsigned short*)(ws + 4194304);      // alias (after qkv10)
  float*          biasP = (float*)(ws + 6291456);               // 12,288
  unsigned short* WRw   = (unsigned short*)(ws + 6303744);      // 65,536
  float*          biasWR= (float*)(ws + 6369280);               // 128
  unsigned short* Wob   = (unsigned short*)(ws + 6369408);      // 2,097,152
  unsigned short* Xb    = (unsigned short*)(ws + 8466560);      // 33,554,432
  unsigned short* Ob    = Xb;                                   // alias (after qkv10)
  unsigned short* Qb    = (unsigned short*)(ws + 42020992);     // 33,554,432
  unsigned short* Kb    = (unsigned short*)(ws + 75575424);     // 33,554,432
  unsigned short* Vb    = (unsigned short*)(ws + 109129856);    // 33,554,432
  float*          WRf   = (float*)(ws + 142684288);             // 2,097,152

  float* Out0 = (float*)d_out;
  float* Aout = Out0 + (size_t)ROWS * DM;   // second tuple output

  k_cast_x<<<dim3(8192), dim3(256), 0, stream>>>(X, Xb);
  k_pack_w<<<dim3(4128), dim3(256), 0, stream>>>(Wq, Wk, Wv, Wo, Ww, Wr,
                                                 bq, bk, bv, bw, br,
                                                 Wpack, biasP, WRw, biasWR, Wob);
  k_wr<<<dim3(128), dim3(256), 0, stream>>>(Xb, WRw, biasWR, WRf);
  k_gemm_qkv10<<<dim3(3072), dim3(256), 0, stream>>>(Xb, Wpack, biasP, WRf, Qb, Kb, Vb);
  k_gemm_A<<<dim3(256), dim3(256), 0, stream>>>(Kb, Vb, Apart);
  k_reduceA<<<dim3(128), dim3(256), 0, stream>>>(Apart, Aout, Abf);
  k_gemm_o2<<<dim3(2048), dim3(256), 0, stream>>>(Qb, Abf, WRf, Ob);
  k_gemm_out10<<<dim3(256), dim3(512), 0, stream>>>(Ob, Wob, bo, Out0);
}

// Round 11
// 240.342 us; speedup vs baseline: 1.0751x; 1.0751x over previous
//
#include <hip/hip_runtime.h>
#include <cstdint>
#include <cstddef>

// ---------------------------------------------------------------------------
// NAMAttention round 11 == round 6 byte-exact (best measured total: 241.9us).
//  - qkv + out-proj GEMMs: 256x256 tile, BK=32, DEPTH-4 ring LDS (4 x 32 KiB),
//    counted vmcnt(4) + reads-one-tile-ahead with counted lgkmcnt(4).
//    Conflict-free chunk swizzle c ^ ((r>>1)&3) both sides.
//  - cast_x separate; k_wr reads Xb bf16; gemm_A split-K=2; reduceA; o2.
// Rationale: r10 falsified the last lever (4 blocks/CU — occupancy stuck at
// 40%); five sync schedules plateau qkv at 144-160us; byte-identical tails
// vary +-20us across sessions; r6 holds the best measured total -> restore it.
// ---------------------------------------------------------------------------

typedef __bf16 bf16x8 __attribute__((ext_vector_type(8)));
typedef float  f32x4  __attribute__((ext_vector_type(4)));
typedef unsigned short u16x8 __attribute__((ext_vector_type(8)));
typedef unsigned short u16x4 __attribute__((ext_vector_type(4)));

#define ROWS 16384      // S*B
#define DM   1024

__device__ __forceinline__ unsigned short f2bf(float f) {
  unsigned int u = __builtin_bit_cast(unsigned int, f);
  u += 0x7FFFu + ((u >> 16) & 1u);            // round-to-nearest-even
  return (unsigned short)(u >> 16);
}
__device__ __forceinline__ float bf2f(unsigned short h) {
  unsigned int u = ((unsigned int)h) << 16;
  return __builtin_bit_cast(float, u);
}
__device__ __forceinline__ float sigm(float x) { return 1.0f / (1.0f + __expf(-x)); }

__device__ __forceinline__ void gload_lds16(const void* g, void* l) {
  __builtin_amdgcn_global_load_lds((__attribute__((address_space(1))) void*)(g),
                                   (__attribute__((address_space(3))) void*)(l),
                                   16, 0, 0);
}

// ---------------- cast input to bf16 ----------------
__global__ __launch_bounds__(256) void k_cast_x(const float* __restrict__ X,
                                                unsigned short* __restrict__ Xb) {
  size_t i = ((size_t)blockIdx.x * 256 + threadIdx.x) * 8;
  f32x4 a = *(const f32x4*)(X + i);
  f32x4 b = *(const f32x4*)(X + i + 4);
  u16x8 o;
  o[0] = f2bf(a[0]); o[1] = f2bf(a[1]); o[2] = f2bf(a[2]); o[3] = f2bf(a[3]);
  o[4] = f2bf(b[0]); o[5] = f2bf(b[1]); o[6] = f2bf(b[2]); o[7] = f2bf(b[3]);
  *(u16x8*)(Xb + i) = o;
}

// ---------------- pack weights (bf16) + biases ----------------
__global__ __launch_bounds__(256) void k_pack_w(
    const float* __restrict__ Wq, const float* __restrict__ Wk, const float* __restrict__ Wv,
    const float* __restrict__ Wo, const float* __restrict__ Ww, const float* __restrict__ Wr,
    const float* __restrict__ bq, const float* __restrict__ bk, const float* __restrict__ bv,
    const float* __restrict__ bw, const float* __restrict__ br,
    unsigned short* __restrict__ Wpack, float* __restrict__ biasP,
    unsigned short* __restrict__ WRw, float* __restrict__ biasWR,
    unsigned short* __restrict__ Wob) {
  int r = blockIdx.x, t = threadIdx.x;
  const float* src; float bias = 0.0f; unsigned short* dst; float* bdst;
  if (r < 1024)      { src = Wq + (size_t)r * DM;          bias = bq[r];        dst = Wpack + (size_t)r * DM;          bdst = biasP + r; }
  else if (r < 2048) { src = Wk + (size_t)(r - 1024) * DM; bias = bk[r - 1024]; dst = Wpack + (size_t)r * DM;          bdst = biasP + r; }
  else if (r < 3072) { src = Wv + (size_t)(r - 2048) * DM; bias = bv[r - 2048]; dst = Wpack + (size_t)r * DM;          bdst = biasP + r; }
  else if (r < 3088) { src = Ww + (size_t)(r - 3072) * DM; bias = bw[r - 3072]; dst = WRw + (size_t)(r - 3072) * DM;   bdst = biasWR + (r - 3072); }
  else if (r < 3104) { src = Wr + (size_t)(r - 3088) * DM; bias = br[r - 3088]; dst = WRw + (size_t)(r - 3072) * DM;   bdst = biasWR + (r - 3072); }
  else               { src = Wo + (size_t)(r - 3104) * DM;                      dst = Wob + (size_t)(r - 3104) * DM;   bdst = nullptr; }
  int c = t * 4;
  f32x4 v = *(const f32x4*)(src + c);
  u16x4 o;
  o[0] = f2bf(v[0]); o[1] = f2bf(v[1]); o[2] = f2bf(v[2]); o[3] = f2bf(v[3]);
  *(u16x4*)(dst + c) = o;
  if (t == 0 && bdst) *bdst = bias;
}

// ---------------- w/r logits: WRf[row,0..31] = X @ [Ww;Wr]^T + b ----------------
__global__ __launch_bounds__(256) void k_wr(const unsigned short* __restrict__ Xb,
                                            const unsigned short* __restrict__ WRw,
                                            const float* __restrict__ biasWR,
                                            float* __restrict__ WRf) {
  __shared__ __bf16 sA[128 * 64];
  __shared__ __bf16 sB[32 * 64];
  int t = threadIdx.x, lane = t & 63, wid = t >> 6;
  int m0 = blockIdx.x * 128;
  int l15 = lane & 15, l4 = lane >> 4;
  f32x4 acc[2][2];
#pragma unroll
  for (int i = 0; i < 2; ++i)
#pragma unroll
    for (int j = 0; j < 2; ++j) acc[i][j] = (f32x4){0.f, 0.f, 0.f, 0.f};
  int srow = t >> 3, schunk = (t & 7) * 8;
  for (int kt = 0; kt < DM; kt += 64) {
#pragma unroll
    for (int c = 0; c < 4; ++c)
      gload_lds16(Xb + (size_t)(m0 + c * 32 + srow) * DM + kt + schunk,
                  (void*)(sA + c * 2048 + wid * 512));
    gload_lds16(WRw + (size_t)srow * DM + kt + schunk, (void*)(sB + wid * 512));
    __syncthreads();
#pragma unroll
    for (int ks = 0; ks < 2; ++ks) {
      bf16x8 fa[2], fb[2];
#pragma unroll
      for (int mi = 0; mi < 2; ++mi)
        fa[mi] = *(const bf16x8*)(sA + (wid * 32 + mi * 16 + l15) * 64 + (ks * 4 + l4) * 8);
#pragma unroll
      for (int ni = 0; ni < 2; ++ni)
        fb[ni] = *(const bf16x8*)(sB + (ni * 16 + l15) * 64 + (ks * 4 + l4) * 8);
#pragma unroll
      for (int mi = 0; mi < 2; ++mi)
#pragma unroll
        for (int ni = 0; ni < 2; ++ni)
          acc[mi][ni] = __builtin_amdgcn_mfma_f32_16x16x32_bf16(fa[mi], fb[ni], acc[mi][ni], 0, 0, 0);
    }
    __syncthreads();
  }
#pragma unroll
  for (int mi = 0; mi < 2; ++mi)
#pragma unroll
    for (int e = 0; e < 4; ++e) {
      int row = m0 + wid * 32 + mi * 16 + 4 * l4 + e;
#pragma unroll
      for (int ni = 0; ni < 2; ++ni)
        WRf[(size_t)row * 32 + ni * 16 + l15] = acc[mi][ni][e] + biasWR[ni * 16 + l15];
    }
}

// ========== 256x256 depth-4 counted-vmcnt + read-ahead core (BK=32) ==========
#define VMW(N)  asm volatile("s_waitcnt vmcnt(" #N ")" ::: "memory")
#define LGKM(N) asm volatile("s_waitcnt lgkmcnt(" #N ")" ::: "memory")
#define SB0     __builtin_amdgcn_sched_barrier(0)

__device__ __forceinline__ void stageT(const unsigned short* __restrict__ Asrc,
                                       const unsigned short* __restrict__ Bsrc,
                                       int kt, __bf16* sm, int sb, int w) {
#pragma unroll
  for (int c = 0; c < 2; ++c)
    gload_lds16(Asrc + (size_t)c * 128 * DM + kt, (void*)(sm + sb + c * 4096 + w * 512));
#pragma unroll
  for (int c = 0; c < 2; ++c)
    gload_lds16(Bsrc + (size_t)c * 128 * DM + kt, (void*)(sm + sb + 8192 + c * 4096 + w * 512));
}

__device__ __forceinline__ void rdFA(bf16x8 (&fa)[8], const __bf16* base, const int (&aoff)[8]) {
#pragma unroll
  for (int mi = 0; mi < 8; ++mi) fa[mi] = *(const bf16x8*)(base + aoff[mi]);
}
__device__ __forceinline__ void rdFB(bf16x8 (&fb)[4], const __bf16* base, const int (&boff)[4]) {
#pragma unroll
  for (int ni = 0; ni < 4; ++ni) fb[ni] = *(const bf16x8*)(base + boff[ni]);
}

#define MFMA32(FB)                                                                   \
  do {                                                                               \
    __builtin_amdgcn_s_setprio(1);                                                   \
    _Pragma("unroll") for (int mi = 0; mi < 8; ++mi)                                 \
    _Pragma("unroll") for (int ni = 0; ni < 4; ++ni)                                 \
      acc[mi][ni] = __builtin_amdgcn_mfma_f32_16x16x32_bf16(fa[mi], FB[ni],          \
                                                            acc[mi][ni], 0, 0, 0);  \
    __builtin_amdgcn_s_setprio(0);                                                   \
    SB0;                                                                             \
  } while (0)

__device__ __forceinline__ void gemm_d4(const unsigned short* __restrict__ Ag,
                                        const unsigned short* __restrict__ Bg,
                                        __bf16* sm, f32x4 (&acc)[8][4],
                                        int m0, int n0, int lane, int w) {
  const int wm = w >> 2, wn = w & 3;
  const int l15 = lane & 15, l4 = lane >> 4;
  const int t = w * 64 + lane;
  const int srow = t >> 2;                              // 0..127
  const int schunk = ((t & 3) ^ ((srow >> 1) & 3)) * 8; // swizzled source chunk
  const unsigned short* Asrc = Ag + (size_t)(m0 + srow) * DM + schunk;
  const unsigned short* Bsrc = Bg + (size_t)(n0 + srow) * DM + schunk;

  int aoff[8], boff[4];
#pragma unroll
  for (int mi = 0; mi < 8; ++mi) {
    int r = wm * 128 + mi * 16 + l15;
    aoff[mi] = r * 32 + ((l4 ^ ((r >> 1) & 3)) << 3);
  }
#pragma unroll
  for (int ni = 0; ni < 4; ++ni) {
    int r = wn * 64 + ni * 16 + l15;
    boff[ni] = 8192 + r * 32 + ((l4 ^ ((r >> 1) & 3)) << 3);
  }

  bf16x8 fa[8], fbA[4], fbB[4];
  // ---- prologue: stage tiles 0,1,2; read frags(0); confirm tile1 ----
  stageT(Asrc, Bsrc, 0,  sm, 0,     w);
  stageT(Asrc, Bsrc, 32, sm, 16384, w);
  stageT(Asrc, Bsrc, 64, sm, 32768, w);
  VMW(8);                                  // tile0 landed (own loads)
  __builtin_amdgcn_s_barrier(); SB0;       // cross-wave tile0
  rdFB(fbA, sm, boff);                     // fb(0)
  rdFA(fa, sm, aoff);                      // fa(0)
  VMW(4);                                  // tile1 landed
  __builtin_amdgcn_s_barrier(); SB0;

  int sb = 49152;                          // stage dest: buf (t+3)%4, t=0 -> 3
  int rb = 16384;                          // read src: buf (t+1)%4, t=0 -> 1
  // ---- steady: t = 0..27 (14 pairs) ----
  for (int i = 0; i < 14; ++i) {
    stageT(Asrc, Bsrc, (2 * i + 3) * 32, sm, sb, w); sb = (sb + 16384) & 65535;
    rdFB(fbB, sm + rb, boff);
    LGKM(4); SB0;                          // fa(t), fbA(t) confirmed
    MFMA32(fbA);
    rdFA(fa, sm + rb, aoff); rb = (rb + 16384) & 65535;
    VMW(4);                                // stage(t+2) confirmed
    __builtin_amdgcn_s_barrier(); SB0;
    stageT(Asrc, Bsrc, (2 * i + 4) * 32, sm, sb, w); sb = (sb + 16384) & 65535;
    rdFB(fbA, sm + rb, boff);
    LGKM(4); SB0;
    MFMA32(fbB);
    rdFA(fa, sm + rb, aoff); rb = (rb + 16384) & 65535;
    VMW(4);
    __builtin_amdgcn_s_barrier(); SB0;
  }
  // ---- t=28: stage tile 31 (last) ----
  stageT(Asrc, Bsrc, 992, sm, sb, w);
  rdFB(fbB, sm + rb, boff);
  LGKM(4); SB0;
  MFMA32(fbA);
  rdFA(fa, sm + rb, aoff); rb = (rb + 16384) & 65535;
  VMW(4);                                  // stage(30) confirmed
  __builtin_amdgcn_s_barrier(); SB0;
  // ---- t=29 ----
  rdFB(fbA, sm + rb, boff);
  LGKM(4); SB0;
  MFMA32(fbB);
  rdFA(fa, sm + rb, aoff); rb = (rb + 16384) & 65535;
  VMW(0);                                  // stage(31) confirmed
  __builtin_amdgcn_s_barrier(); SB0;
  // ---- t=30 ----
  rdFB(fbB, sm + rb, boff);
  LGKM(4); SB0;
  MFMA32(fbA);
  rdFA(fa, sm + rb, aoff);
  // ---- t=31 ----
  LGKM(0); SB0;
  MFMA32(fbB);
}

// ---------------- fused QKV GEMM (depth-4 core) + norm/gate epilogue ---------
__global__ __launch_bounds__(512, 2) void k_gemm_qkv6(
    const unsigned short* __restrict__ Xb, const unsigned short* __restrict__ Wpack,
    const float* __restrict__ biasP, const float* __restrict__ WRf,
    unsigned short* __restrict__ Qb, unsigned short* __restrict__ Kb,
    unsigned short* __restrict__ Vb) {
  __shared__ __bf16 sm[65536];                     // 128 KiB, 4 buffers
  const int t = threadIdx.x, lane = t & 63, w = t >> 6;
  const int wm = w >> 2, wn = w & 3;
  const int l15 = lane & 15, l4 = lane >> 4;
  int orig = blockIdx.x;
  int wg = (orig & 7) * 96 + (orig >> 3);          // bijective XCD swizzle (768=8*96)
  const int m0 = (wg & 63) << 8;                   // 64 m-tiles of 256
  const int n0 = (wg >> 6) << 8;                   // 12 n-tiles of 256
  f32x4 acc[8][4];
#pragma unroll
  for (int i = 0; i < 8; ++i)
#pragma unroll
    for (int j = 0; j < 4; ++j) acc[i][j] = (f32x4){0.f, 0.f, 0.f, 0.f};
  gemm_d4(Xb, Wpack, sm, acc, m0, n0, lane, w);

  // ---- epilogue: each wave's 64-col stripe == one head ----
  const int colbase = n0 + wn * 64;
  float bb[4];
#pragma unroll
  for (int ni = 0; ni < 4; ++ni) bb[ni] = biasP[colbase + ni * 16 + l15];

  if (colbase < 2048) {
    unsigned short* dstp = (colbase < 1024) ? Qb : Kb;
    int coff = (colbase < 1024) ? colbase : (colbase - 1024);
#pragma unroll
    for (int mi = 0; mi < 8; ++mi)
#pragma unroll
      for (int e = 0; e < 4; ++e) {
        float v[4]; float ssq = 0.f;
#pragma unroll
        for (int ni = 0; ni < 4; ++ni) { v[ni] = acc[mi][ni][e] + bb[ni]; ssq += v[ni] * v[ni]; }
        ssq += __shfl_xor(ssq, 1);
        ssq += __shfl_xor(ssq, 2);
        ssq += __shfl_xor(ssq, 4);
        ssq += __shfl_xor(ssq, 8);       // full 64-col head
        float sc = 1.0f / fmaxf(sqrtf(ssq), 1e-12f);
        int row = m0 + wm * 128 + mi * 16 + 4 * l4 + e;
#pragma unroll
        for (int ni = 0; ni < 4; ++ni)
          dstp[(size_t)row * DM + coff + ni * 16 + l15] = f2bf(v[ni] * sc);
      }
  } else {
    int hv = (colbase - 2048) >> 6;
    int coff = colbase - 2048;
#pragma unroll
    for (int mi = 0; mi < 8; ++mi)
#pragma unroll
      for (int e = 0; e < 4; ++e) {
        int row = m0 + wm * 128 + mi * 16 + 4 * l4 + e;
        float wgt = sigm(WRf[(size_t)row * 32 + hv]);
#pragma unroll
        for (int ni = 0; ni < 4; ++ni)
          Vb[(size_t)row * DM + coff + ni * 16 + l15] = f2bf((acc[mi][ni][e] + bb[ni]) * wgt);
      }
  }
}

// ---------------- final projection (depth-4 core): Out = Ob @ Wo^T + bo ------
__global__ __launch_bounds__(512, 2) void k_gemm_out6(
    const unsigned short* __restrict__ Ob, const unsigned short* __restrict__ Wob,
    const float* __restrict__ bo, float* __restrict__ Out) {
  __shared__ __bf16 sm[65536];
  const int t = threadIdx.x, lane = t & 63, w = t >> 6;
  const int wm = w >> 2, wn = w & 3;
  const int l15 = lane & 15, l4 = lane >> 4;
  int orig = blockIdx.x;
  int wg = (orig & 7) * 32 + (orig >> 3);          // 256 = 8*32
  const int m0 = (wg & 63) << 8;                   // 64 m-tiles
  const int n0 = (wg >> 6) << 8;                   // 4 n-tiles
  f32x4 acc[8][4];
#pragma unroll
  for (int i = 0; i < 8; ++i)
#pragma unroll
    for (int j = 0; j < 4; ++j) acc[i][j] = (f32x4){0.f, 0.f, 0.f, 0.f};
  gemm_d4(Ob, Wob, sm, acc, m0, n0, lane, w);

  float bb[4];
#pragma unroll
  for (int ni = 0; ni < 4; ++ni) bb[ni] = bo[n0 + wn * 64 + ni * 16 + l15];
#pragma unroll
  for (int mi = 0; mi < 8; ++mi)
#pragma unroll
    for (int e = 0; e < 4; ++e) {
      int row = m0 + wm * 128 + mi * 16 + 4 * l4 + e;
#pragma unroll
      for (int ni = 0; ni < 4; ++ni) {
        int col = n0 + wn * 64 + ni * 16 + l15;
        Out[(size_t)row * DM + col] = acc[mi][ni][e] + bb[ni];
      }
    }
}

// ---------------- gemm_A split-K=2 ----------------
__global__ __launch_bounds__(256, 2) void k_gemm_A(const unsigned short* __restrict__ Kb,
                                                   const unsigned short* __restrict__ Vb,
                                                   float* __restrict__ Apart) {
  __shared__ __bf16 sK[64 * 64];
  __shared__ __bf16 sV[64 * 64];
  int t = threadIdx.x, lane = t & 63, wid = t >> 6;
  int bn = blockIdx.x & 127, sk = blockIdx.x >> 7;
  int b = bn >> 4, n = bn & 15;
  f32x4 acc[4];
#pragma unroll
  for (int j = 0; j < 4; j++) acc[j] = (f32x4){0.f, 0.f, 0.f, 0.f};
  int lrow = lane >> 3, lcol = (lane & 7) * 8;

  for (int st = sk * 1024; st < (sk + 1) * 1024; st += 64) {
#pragma unroll
    for (int c = 0; c < 2; c++) {
      int r0 = wid * 16 + c * 8;
      size_t g = ((size_t)(st + r0 + lrow) * 8 + b) * DM + n * 64 + lcol;
      gload_lds16(Kb + g, (void*)(sK + r0 * 64));
      gload_lds16(Vb + g, (void*)(sV + r0 * 64));
    }
    __syncthreads();
#pragma unroll
    for (int kk = 0; kk < 64; kk += 32) {
      bf16x8 av, bv[4];
#pragma unroll
      for (int e = 0; e < 8; e++)
        av[e] = sV[(kk + 8 * (lane >> 4) + e) * 64 + wid * 16 + (lane & 15)];
#pragma unroll
      for (int jn = 0; jn < 4; jn++)
#pragma unroll
        for (int e = 0; e < 8; e++)
          bv[jn][e] = sK[(kk + 8 * (lane >> 4) + e) * 64 + jn * 16 + (lane & 15)];
#pragma unroll
      for (int jn = 0; jn < 4; jn++)
        acc[jn] = __builtin_amdgcn_mfma_f32_16x16x32_bf16(av, bv[jn], acc[jn], 0, 0, 0);
    }
    __syncthreads();
  }
  float* Ap = Apart + (size_t)(sk * 128 + bn) * 4096;
#pragma unroll
  for (int jn = 0; jn < 4; jn++) {
#pragma unroll
    for (int e = 0; e < 4; e++) {
      int i = wid * 16 + 4 * (lane >> 4) + e;
      int j = jn * 16 + (lane & 15);
      Ap[i * 64 + j] = acc[jn][e];
    }
  }
}

// ---------------- reduce split-K partials ----------------
__global__ __launch_bounds__(256) void k_reduceA(const float* __restrict__ Apart,
                                                 float* __restrict__ Aout,
                                                 unsigned short* __restrict__ Abf) {
  int bn = blockIdx.x, t = threadIdx.x;
  size_t base = (size_t)bn * 4096 + t * 16;
#pragma unroll
  for (int j = 0; j < 4; ++j) {
    f32x4 x = *(const f32x4*)(Apart + base + j * 4);
    f32x4 y = *(const f32x4*)(Apart + (size_t)128 * 4096 + base + j * 4);
    x += y;
    *(f32x4*)(Aout + base + j * 4) = x;
    u16x4 o;
    o[0] = f2bf(x[0]); o[1] = f2bf(x[1]); o[2] = f2bf(x[2]); o[3] = f2bf(x[3]);
    *(u16x4*)(Abf + base + j * 4) = o;
  }
}

// ---------------- out2 = r * (qhat @ A^T) ----------------
__global__ __launch_bounds__(256, 2) void k_gemm_o2(const unsigned short* __restrict__ Qb,
                                                    const unsigned short* __restrict__ Abf,
                                                    const float* __restrict__ WRf,
                                                    unsigned short* __restrict__ Ob) {
  __shared__ __bf16 sQ[128 * 64];
  __shared__ __bf16 sA[64 * 64];
  int t = threadIdx.x, lane = t & 63, wid = t >> 6;
  int bn = blockIdx.x & 127, stile = blockIdx.x >> 7;
  int b = bn >> 4, n = bn & 15;
  int s0 = stile * 128;
  int lrow = lane >> 3, lcol = (lane & 7) * 8;
#pragma unroll
  for (int c = 0; c < 4; c++) {
    int r0 = wid * 32 + c * 8;
    gload_lds16(Qb + ((size_t)(s0 + r0 + lrow) * 8 + b) * DM + n * 64 + lcol,
                (void*)(sQ + r0 * 64));
  }
#pragma unroll
  for (int c = 0; c < 2; c++) {
    int r0 = wid * 16 + c * 8;
    gload_lds16(Abf + (size_t)bn * 4096 + (size_t)(r0 + lrow) * 64 + lcol,
                (void*)(sA + r0 * 64));
  }
  __syncthreads();
  f32x4 acc[2][4];
#pragma unroll
  for (int i = 0; i < 2; i++)
#pragma unroll
    for (int j = 0; j < 4; j++) acc[i][j] = (f32x4){0.f, 0.f, 0.f, 0.f};
#pragma unroll
  for (int kk = 0; kk < 64; kk += 32) {
    bf16x8 aq[2], bA[4];
#pragma unroll
    for (int mi = 0; mi < 2; mi++)
      aq[mi] = *(const bf16x8*)(sQ + (wid * 32 + mi * 16 + (lane & 15)) * 64 + kk + 8 * (lane >> 4));
#pragma unroll
    for (int ni = 0; ni < 4; ni++)
      bA[ni] = *(const bf16x8*)(sA + (ni * 16 + (lane & 15)) * 64 + kk + 8 * (lane >> 4));
#pragma unroll
    for (int mi = 0; mi < 2; mi++)
#pragma unroll
      for (int ni = 0; ni < 4; ni++)
        acc[mi][ni] = __builtin_amdgcn_mfma_f32_16x16x32_bf16(aq[mi], bA[ni], acc[mi][ni], 0, 0, 0);
  }
#pragma unroll
  for (int mi = 0; mi < 2; mi++) {
#pragma unroll
    for (int e = 0; e < 4; e++) {
      int srow = wid * 32 + mi * 16 + 4 * (lane >> 4) + e;
      size_t row = (size_t)(s0 + srow) * 8 + b;
      float rv = sigm(WRf[row * 32 + 16 + n]);
#pragma unroll
      for (int ni = 0; ni < 4; ni++)
        Ob[row * DM + n * 64 + ni * 16 + (lane & 15)] = f2bf(acc[mi][ni][e] * rv);
    }
  }
}

// ---------------------------------------------------------------------------
extern "C" void kernel_launch(void* const* d_in, const int* in_sizes, int n_in,
                              void* d_out, int out_size, void* d_ws, size_t ws_size,
                              hipStream_t stream) {
  (void)in_sizes; (void)n_in; (void)out_size; (void)ws_size;
  const float* X  = (const float*)d_in[0];
  const float* Wq = (const float*)d_in[1];  const float* bq = (const float*)d_in[2];
  const float* Wk = (const float*)d_in[3];  const float* bk = (const float*)d_in[4];
  const float* Wv = (const float*)d_in[5];  const float* bv = (const float*)d_in[6];
  const float* Wo = (const float*)d_in[7];  const float* bo = (const float*)d_in[8];
  const float* Ww = (const float*)d_in[9];  const float* bw = (const float*)d_in[10];
  const float* Wr = (const float*)d_in[11]; const float* br = (const float*)d_in[12];

  char* ws = (char*)d_ws;
  unsigned short* Wpack = (unsigned short*)(ws + 0);            // 6,291,456
  float*          Apart = (float*)(ws + 0);                     // alias (after qkv6)
  unsigned short* Abf   = (unsigned short*)(ws + 4194304);      // alias (after qkv6)
  float*          biasP = (float*)(ws + 6291456);               // 12,288
  unsigned short* WRw   = (unsigned short*)(ws + 6303744);      // 65,536
  float*          biasWR= (float*)(ws + 6369280);               // 128
  unsigned short* Wob   = (unsigned short*)(ws + 6369408);      // 2,097,152
  unsigned short* Xb    = (unsigned short*)(ws + 8466560);      // 33,554,432
  unsigned short* Ob    = Xb;                                   // alias (after qkv6)
  unsigned short* Qb    = (unsigned short*)(ws + 42020992);     // 33,554,432
  unsigned short* Kb    = (unsigned short*)(ws + 75575424);     // 33,554,432
  unsigned short* Vb    = (unsigned short*)(ws + 109129856);    // 33,554,432
  float*          WRf   = (float*)(ws + 142684288);             // 2,097,152

  float* Out0 = (float*)d_out;
  float* Aout = Out0 + (size_t)ROWS * DM;   // second tuple output

  k_cast_x<<<dim3(8192), dim3(256), 0, stream>>>(X, Xb);
  k_pack_w<<<dim3(4128), dim3(256), 0, stream>>>(Wq, Wk, Wv, Wo, Ww, Wr,
                                                 bq, bk, bv, bw, br,
                                                 Wpack, biasP, WRw, biasWR, Wob);
  k_wr<<<dim3(128), dim3(256), 0, stream>>>(Xb, WRw, biasWR, WRf);
  k_gemm_qkv6<<<dim3(768), dim3(512), 0, stream>>>(Xb, Wpack, biasP, WRf, Qb, Kb, Vb);
  k_gemm_A<<<dim3(256), dim3(256), 0, stream>>>(Kb, Vb, Apart);
  k_reduceA<<<dim3(128), dim3(256), 0, stream>>>(Apart, Aout, Abf);
  k_gemm_o2<<<dim3(2048), dim3(256), 0, stream>>>(Qb, Abf, WRf, Ob);
  k_gemm_out6<<<dim3(256), dim3(512), 0, stream>>>(Ob, Wob, bo, Out0);
}